// Round 1
// baseline (272.687 us; speedup 1.0000x reference)
//
#include <hip/hip_runtime.h>
#include <hip/hip_bf16.h>

// PopulationODE: explicit Euler over L=512 grid points, B=32768 trajectories,
// 4 coupled states (A,T,N,C), 21 scalar weights. Output [L,4,B] fp32 = 256 MiB.
// Memory(write)-bound: one thread per trajectory, states in registers,
// coalesced dword stores (lane b -> address ...*B + b).

#define ODE_L 512
#define ODE_B 32768

__global__ __launch_bounds__(64) void population_ode_kernel(
    const float* __restrict__ s_grid,   // [L]
    const float* __restrict__ y0,       // [4, B]
    const float* __restrict__ w,        // [21]
    float* __restrict__ out)            // [L, 4, B]
{
    __shared__ float sh_s[ODE_L];

    const int tid = threadIdx.x;
    // Stage s_grid into LDS (64 threads x 8 values).
    #pragma unroll
    for (int i = tid; i < ODE_L; i += 64) {
        sh_s[i] = s_grid[i];
    }

    // Hoist weights into registers (uniform address -> scalar loads).
    const float w0  = w[0],  w1  = w[1],  w2  = w[2];
    const float w3  = w[3],  w4  = w[4],  w5  = w[5],  w6  = w[6],  w7  = w[7],  w8  = w[8];
    const float w9  = w[9],  w10 = w[10], w11 = w[11], w12 = w[12], w13 = w[13], w14 = w[14];
    const float w15 = w[15], w16 = w[16], w17 = w[17], w18 = w[18], w19 = w[19], w20 = w[20];

    __syncthreads();

    const int b = blockIdx.x * 64 + tid;

    float A = y0[0 * ODE_B + b];
    float T = y0[1 * ODE_B + b];
    float N = y0[2 * ODE_B + b];
    float C = y0[3 * ODE_B + b];

    // Row 0 of the output is y0 itself.
    out[0 * ODE_B + b] = A;
    out[1 * ODE_B + b] = T;
    out[2 * ODE_B + b] = N;
    out[3 * ODE_B + b] = C;

    float s_prev = sh_s[0];

    for (int i = 1; i < ODE_L; ++i) {
        const float s_cur = sh_s[i];
        const float h = s_cur - s_prev;   // h_{i-1} = s[i] - s[i-1]
        s_prev = s_cur;

        // RHS evaluated at the OLD state (all four d* before any update).
        const float dA = w0  + w1  * A + w2  * A * A;
        const float dT = w3  + w4  * T + w5  * T * T + w6  * A + w7  * A * A + w8  * A * T;
        const float dN = w9  + w10 * N + w11 * N * N + w12 * T + w13 * T * T + w14 * T * N;
        const float dC = w15 + w16 * C + w17 * C * C + w18 * N + w19 * N * N + w20 * N * C;

        A = A + h * dA;
        T = T + h * dT;
        N = N + h * dN;
        C = C + h * dC;

        const size_t base = (size_t)i * (4 * ODE_B) + (size_t)b;
        out[base + 0 * ODE_B] = A;
        out[base + 1 * ODE_B] = T;
        out[base + 2 * ODE_B] = N;
        out[base + 3 * ODE_B] = C;
    }
}

extern "C" void kernel_launch(void* const* d_in, const int* in_sizes, int n_in,
                              void* d_out, int out_size, void* d_ws, size_t ws_size,
                              hipStream_t stream) {
    (void)in_sizes; (void)n_in; (void)d_ws; (void)ws_size; (void)out_size;

    const float* s_grid = (const float*)d_in[0];
    const float* y0     = (const float*)d_in[1];
    const float* w      = (const float*)d_in[2];
    float* out          = (float*)d_out;

    // B = 32768 trajectories, 64 threads/block -> 512 blocks (2 waves/CU on 256 CUs).
    dim3 grid(ODE_B / 64);
    dim3 block(64);
    population_ode_kernel<<<grid, block, 0, stream>>>(s_grid, y0, w, out);
}